// Round 1
// baseline (2401.000 us; speedup 1.0000x reference)
//
#include <hip/hip_runtime.h>
#include <math.h>

#define BTOT 1024
#define LEN  2048
#define T    100
#define HID  128
#define BPW  4   // batches per workgroup in the LSTM kernel

// time embedding, argument scaled in f64 (matches np-f64 reference arithmetic)
// dims: sin(t), cos(t*10^-1.6), sin(t*10^-3.2), cos(t*10^-4.8), sin(t*10^-6.4)
__device__ __forceinline__ void temb(double t, float e[5]) {
  e[0] = sinf((float)t);
  e[1] = cosf((float)(t * 0.025118864315095794));
  e[2] = sinf((float)(t * 6.309573444801933e-04));
  e[3] = cosf((float)(t * 1.5848931924611134e-05));
  e[4] = sinf((float)(t * 3.9810717055349735e-07));
}

__device__ __forceinline__ float sig(float x) { return 1.0f / (1.0f + expf(-x)); }

// ---------------- Phase A: attention precompute ----------------
// grid = 1024 (one block per batch), block = 256.
// Each thread owns 16 events (8 from a1, 8 from a2); embeddings live in registers.
__global__ __launch_bounds__(256) void attn_k(const float* __restrict__ ta1,
                                              const float* __restrict__ ta2,
                                              float* __restrict__ att) {
  const int b = blockIdx.x, tid = threadIdx.x;
  const int wave = tid >> 6, lane = tid & 63;

  __shared__ float qlds[T][5];
  __shared__ float smax[4];
  __shared__ float ssum[4][7];

  if (tid < T) {
    double ct = (double)(tid + 1) * 0.1;   // cur_times in f64 (np ref semantics)
    float q[5]; temb(ct, q);
#pragma unroll
    for (int j = 0; j < 5; j++) qlds[tid][j] = q[j] * 0.35355339059327373f; // fold 1/sqrt(8)
  }

  float tt[16];
#pragma unroll
  for (int i = 0; i < 8; i++) tt[i]     = ta1[b * LEN + tid + 256 * i];
#pragma unroll
  for (int i = 0; i < 8; i++) tt[8 + i] = ta2[b * LEN + tid + 256 * i];

  float emb[16][5];
#pragma unroll
  for (int i = 0; i < 16; i++) temb((double)tt[i], emb[i]);

  __syncthreads();

  for (int t = 0; t < T; t++) {
    const float q0 = qlds[t][0], q1 = qlds[t][1], q2 = qlds[t][2],
                q3 = qlds[t][3], q4 = qlds[t][4];
    float sc[16], mx = -1e30f;
#pragma unroll
    for (int i = 0; i < 16; i++) {
      float s = q0 * emb[i][0] + q1 * emb[i][1] + q2 * emb[i][2] +
                q3 * emb[i][3] + q4 * emb[i][4];
      sc[i] = s;
      mx = fmaxf(mx, s);
    }
#pragma unroll
    for (int o = 32; o > 0; o >>= 1) mx = fmaxf(mx, __shfl_xor(mx, o));
    if (lane == 0) smax[wave] = mx;
    __syncthreads();
    mx = fmaxf(fmaxf(smax[0], smax[1]), fmaxf(smax[2], smax[3]));

    float w0 = 0.f, w1 = 0.f, w2 = 0.f, w3 = 0.f, w4 = 0.f, sA = 0.f, sB = 0.f;
#pragma unroll
    for (int i = 0; i < 16; i++) {
      float e = __expf(sc[i] - mx);
      if (i < 8) sA += e; else sB += e;
      w0 += e * emb[i][0]; w1 += e * emb[i][1]; w2 += e * emb[i][2];
      w3 += e * emb[i][3]; w4 += e * emb[i][4];
    }
    float r[7] = {w0, w1, w2, w3, w4, sA, sB};
#pragma unroll
    for (int j = 0; j < 7; j++) {
#pragma unroll
      for (int o = 32; o > 0; o >>= 1) r[j] += __shfl_xor(r[j], o);
    }
    if (lane == 0) {
#pragma unroll
      for (int j = 0; j < 7; j++) ssum[wave][j] = r[j];
    }
    __syncthreads();
    if (tid == 0) {
      float f[7];
#pragma unroll
      for (int j = 0; j < 7; j++)
        f[j] = ssum[0][j] + ssum[1][j] + ssum[2][j] + ssum[3][j];
      float inv = 1.0f / (f[5] + f[6]);
      float* o8 = &att[(size_t)b * (T * 8) + (size_t)t * 8];
      o8[0] = f[0] * inv; o8[1] = f[1] * inv; o8[2] = f[2] * inv;
      o8[3] = f[3] * inv; o8[4] = f[4] * inv;
      o8[5] = 0.f;                // mental predicate never present in kv
      o8[6] = f[5] * inv;         // attn mass on A1 events
      o8[7] = f[6] * inv;         // attn mass on A2 events
    }
    // no trailing barrier needed: next iteration writes smax (disjoint from
    // ssum) and its own __syncthreads() orders the ssum reuse.
  }
}

// ---------------- Phase B: recurrent LSTM + hazard/event sampling ----------------
// grid = 256 blocks x 512 threads, 4 batches per block.
// Thread r owns gate row r: W_ih row (21) + W_hh row (128) in VGPRs.
// 2 waves/SIMD chip-wide (256 blocks * 8 waves = 2048 waves on 1024 SIMDs).
__global__ __launch_bounds__(512) void lstm_k(const float* __restrict__ att,
                                              const float* __restrict__ u,
                                              const float* __restrict__ Wih,
                                              const float* __restrict__ Whh,
                                              const float* __restrict__ bih,
                                              const float* __restrict__ bhh,
                                              const float* __restrict__ w1g,
                                              const float* __restrict__ b1g,
                                              const float* __restrict__ w2g,
                                              const float* __restrict__ b2g,
                                              float* __restrict__ out) {
  const int tid = threadIdx.x;
  const int bg = blockIdx.x * BPW;
  const int wave = tid >> 6;
  const int ob = tid >> 7, oh = tid & 127;   // (batch, hidden unit) this thread owns

  float wih[21], whh[HID];
#pragma unroll
  for (int k = 0; k < 21; k++) wih[k] = Wih[tid * 21 + k];
#pragma unroll
  for (int k = 0; k < HID; k++) whh[k] = Whh[tid * HID + k];
  const float bias = bih[tid] + bhh[tid];

  float w1r[5], b1r[5], w2r[5];
#pragma unroll
  for (int j = 0; j < 5; j++) { w1r[j] = w1g[j * HID + oh]; b1r[j] = b1g[j]; w2r[j] = w2g[j]; }
  const float b2r = b2g[0];

  __shared__ float xs[BPW][21];
  __shared__ float hx[BPW][HID];
  __shared__ float gl[BPW][512];
  __shared__ float red[8][5];
  __shared__ int st_lastidx[BPW];  // last event time = idx*0.1 (exact f64 reconstruction)
  __shared__ int st_dynidx[BPW];   // dyn_time = idx*0.1
  __shared__ int st_has[BPW];

  for (int i = tid; i < BPW * HID; i += 512) (&hx[0][0])[i] = 0.f;
  if (tid < BPW) { st_lastidx[tid] = 0; st_dynidx[tid] = 0; st_has[tid] = 0; }
  float cx = 0.f;
  __syncthreads();

  for (int t = 0; t < T; t++) {
    // ---- build x = [att_out(8), m_emb(8), ct_emb(5)] in LDS ----
    if (tid < BPW * 8) {                                   // 0..31: attention output
      int b = tid >> 3, j = tid & 7;
      xs[b][j] = att[(size_t)(bg + b) * (T * 8) + (size_t)t * 8 + j];
    } else if (tid < BPW * 8 + BPW * 5) {                  // 32..51: m_emb time part
      int r2 = tid - BPW * 8; int b = r2 / 5, j = r2 % 5;
      float e[5]; temb((double)st_lastidx[b] * 0.1, e);
      xs[b][8 + j] = st_has[b] ? e[j] : 0.f;
    } else if (tid < BPW * 8 + BPW * 5 + BPW * 3) {        // 52..63: m_emb one-hot
      int r2 = tid - BPW * 8 - BPW * 5; int b = r2 / 3, j = r2 % 3;
      xs[b][13 + j] = (j == 0 && st_has[b]) ? 1.0f : 0.f;
    } else if (tid < BPW * 8 + BPW * 5 + BPW * 3 + BPW * 5) { // 64..83: ct_emb(dyn+0.1)
      int r2 = tid - (BPW * 8 + BPW * 5 + BPW * 3); int b = r2 / 5, j = r2 % 5;
      float e[5]; temb((double)(st_dynidx[b] + 1) * 0.1, e);
      xs[b][16 + j] = e[j];
    }
    __syncthreads();

    // ---- gate pre-activations: thread r computes row r for 4 batches ----
    float a0 = bias, a1 = bias, a2 = bias, a3 = bias;
#pragma unroll
    for (int k = 0; k < 21; k++) {
      a0 = fmaf(wih[k], xs[0][k], a0);
      a1 = fmaf(wih[k], xs[1][k], a1);
      a2 = fmaf(wih[k], xs[2][k], a2);
      a3 = fmaf(wih[k], xs[3][k], a3);
    }
#pragma unroll
    for (int k = 0; k < HID; k++) {
      a0 = fmaf(whh[k], hx[0][k], a0);
      a1 = fmaf(whh[k], hx[1][k], a1);
      a2 = fmaf(whh[k], hx[2][k], a2);
      a3 = fmaf(whh[k], hx[3][k], a3);
    }
    gl[0][tid] = a0; gl[1][tid] = a1; gl[2][tid] = a2; gl[3][tid] = a3;
    __syncthreads();

    // ---- LSTM cell update for (ob, oh); gates ordered i,f,g,o ----
    float gi = gl[ob][oh], gf = gl[ob][HID + oh],
          gg = gl[ob][2 * HID + oh], go = gl[ob][3 * HID + oh];
    cx = sig(gf) * cx + sig(gi) * tanhf(gg);
    float h = sig(go) * tanhf(cx);
    hx[ob][oh] = h;

    // ---- hazard head: s5 = w1*hx + b1 ; z = w2*s5 + b2 ----
    float p[5];
#pragma unroll
    for (int j = 0; j < 5; j++) {
      p[j] = w1r[j] * h;
#pragma unroll
      for (int o = 32; o > 0; o >>= 1) p[j] += __shfl_xor(p[j], o);
    }
    if ((tid & 63) == 0) {
#pragma unroll
      for (int j = 0; j < 5; j++) red[wave][j] = p[j];
    }
    __syncthreads();

    if (tid < BPW) {
      int b = tid;
      float z = b2r;
#pragma unroll
      for (int j = 0; j < 5; j++) {
        float s5 = red[2 * b][j] + red[2 * b + 1][j] + b1r[j];
        z += w2r[j] * s5;
      }
      float hz = sig(z);
      float uu = u[(size_t)(bg + b) * T + t];
      int ev = (uu < hz) ? 1 : 0;
      if (ev) { st_lastidx[b] = t + 1; st_has[b] = 1; st_dynidx[b] = 0; }
      else    { st_dynidx[b] = st_dynidx[b] + 1; }
      out[(size_t)t * BTOT + (bg + b)] = hz;
      out[(size_t)(T * BTOT) + (size_t)t * BTOT + (bg + b)] = ev ? 1.0f : 0.f;
    }
    __syncthreads();
  }
}

extern "C" void kernel_launch(void* const* d_in, const int* in_sizes, int n_in,
                              void* d_out, int out_size, void* d_ws, size_t ws_size,
                              hipStream_t stream) {
  const float* ta1 = (const float*)d_in[0];
  const float* ta2 = (const float*)d_in[1];
  const float* u   = (const float*)d_in[2];
  const float* Wih = (const float*)d_in[3];
  const float* Whh = (const float*)d_in[4];
  const float* bih = (const float*)d_in[5];
  const float* bhh = (const float*)d_in[6];
  const float* w1  = (const float*)d_in[7];
  const float* b1  = (const float*)d_in[8];
  const float* w2  = (const float*)d_in[9];
  const float* b2  = (const float*)d_in[10];
  float* out = (float*)d_out;
  float* att = (float*)d_ws;   // 1024*100*8 floats = 3.28 MB scratch

  attn_k<<<dim3(BTOT), dim3(256), 0, stream>>>(ta1, ta2, att);
  lstm_k<<<dim3(BTOT / BPW), dim3(512), 0, stream>>>(att, u, Wih, Whh, bih, bhh,
                                                     w1, b1, w2, b2, out);
}

// Round 2
// 1472.656 us; speedup vs baseline: 1.6304x; 1.6304x over previous
//
#include <hip/hip_runtime.h>
#include <math.h>

#define BTOT 1024
#define LEN  2048
#define T    100
#define HID  128
#define BPW  4   // batches per workgroup in the LSTM kernel

// time embedding, argument scaled in f64 (matches np-f64 reference arithmetic)
// dims: sin(t), cos(t*10^-1.6), sin(t*10^-3.2), cos(t*10^-4.8), sin(t*10^-6.4)
__device__ __forceinline__ void temb(double t, float e[5]) {
  e[0] = sinf((float)t);
  e[1] = cosf((float)(t * 0.025118864315095794));
  e[2] = sinf((float)(t * 6.309573444801933e-04));
  e[3] = cosf((float)(t * 1.5848931924611134e-05));
  e[4] = sinf((float)(t * 3.9810717055349735e-07));
}

__device__ __forceinline__ float sig(float x) { return 1.0f / (1.0f + expf(-x)); }

// ---------------- Phase A: attention precompute ----------------
// grid = 1024 (one block per batch), block = 256 (4 waves).
// Each thread owns 16 events (8 from a1, 8 from a2); embeddings live in
// registers (80 VGPRs) -- launch_bounds(256,2) caps at 256 VGPR so NO spill
// (round-1 default capped at 64 and spilled 4.8 GB of scratch per dispatch).
// Scores are bounded (|q.k|/sqrt(8) <= 5/2.828 = 1.77), so softmax needs no
// max-subtraction: exp(s) <= 5.9, sum <= 2.4e4 -- safe in f32, and it kills
// one shfl-reduce round + one barrier per t.
__global__ __launch_bounds__(256, 2) void attn_k(const float* __restrict__ ta1,
                                                 const float* __restrict__ ta2,
                                                 float* __restrict__ att) {
  const int b = blockIdx.x, tid = threadIdx.x;
  const int wave = tid >> 6, lane = tid & 63;

  __shared__ float qlds[T][5];
  __shared__ float ssum[2][4][7];   // double-buffered per-wave partials

  if (tid < T) {
    double ct = (double)(tid + 1) * 0.1;   // cur_times in f64 (np ref semantics)
    float q[5]; temb(ct, q);
#pragma unroll
    for (int j = 0; j < 5; j++) qlds[tid][j] = q[j] * 0.35355339059327373f; // fold 1/sqrt(8)
  }

  float tt[16];
#pragma unroll
  for (int i = 0; i < 8; i++) tt[i]     = ta1[b * LEN + tid + 256 * i];
#pragma unroll
  for (int i = 0; i < 8; i++) tt[8 + i] = ta2[b * LEN + tid + 256 * i];

  float emb[16][5];
#pragma unroll
  for (int i = 0; i < 16; i++) temb((double)tt[i], emb[i]);

  __syncthreads();

  for (int t = 0; t < T; t++) {
    const float q0 = qlds[t][0], q1 = qlds[t][1], q2 = qlds[t][2],
                q3 = qlds[t][3], q4 = qlds[t][4];

    float w0 = 0.f, w1 = 0.f, w2 = 0.f, w3 = 0.f, w4 = 0.f, sA = 0.f, sB = 0.f;
#pragma unroll
    for (int i = 0; i < 16; i++) {
      float s = q0 * emb[i][0] + q1 * emb[i][1] + q2 * emb[i][2] +
                q3 * emb[i][3] + q4 * emb[i][4];
      float e = __expf(s);
      if (i < 8) sA += e; else sB += e;
      w0 = fmaf(e, emb[i][0], w0);
      w1 = fmaf(e, emb[i][1], w1);
      w2 = fmaf(e, emb[i][2], w2);
      w3 = fmaf(e, emb[i][3], w3);
      w4 = fmaf(e, emb[i][4], w4);
    }
    float r[7] = {w0, w1, w2, w3, w4, sA, sB};
#pragma unroll
    for (int j = 0; j < 7; j++) {
#pragma unroll
      for (int o = 32; o > 0; o >>= 1) r[j] += __shfl_xor(r[j], o);
    }
    if (lane == 0) {
#pragma unroll
      for (int j = 0; j < 7; j++) ssum[t & 1][wave][j] = r[j];
    }
    __syncthreads();
    // finalize rotates across waves; reads buffer (t&1) while iteration t+1
    // writes buffer (t+1)&1 -- disjoint, so one barrier per t suffices.
    if (tid == ((t & 3) << 6)) {
      float f[7];
#pragma unroll
      for (int j = 0; j < 7; j++)
        f[j] = ssum[t & 1][0][j] + ssum[t & 1][1][j] +
               ssum[t & 1][2][j] + ssum[t & 1][3][j];
      float inv = 1.0f / (f[5] + f[6]);
      float* o8 = &att[(size_t)b * (T * 8) + (size_t)t * 8];
      o8[0] = f[0] * inv; o8[1] = f[1] * inv; o8[2] = f[2] * inv;
      o8[3] = f[3] * inv; o8[4] = f[4] * inv;
      o8[5] = 0.f;                // mental predicate never present in kv
      o8[6] = f[5] * inv;         // attn mass on A1 events
      o8[7] = f[6] * inv;         // attn mass on A2 events
    }
  }
}

// ---------------- Phase B: recurrent LSTM + hazard/event sampling ----------------
// grid = 256 blocks x 512 threads, 4 batches per block.
// Thread r owns gate row r: W_ih row (21) + W_hh row (128) in VGPRs (~170 --
// launch_bounds(512,2) caps at 256 so no spill; 3 waves/SIMD >= 2 required).
__global__ __launch_bounds__(512, 2) void lstm_k(const float* __restrict__ att,
                                                 const float* __restrict__ u,
                                                 const float* __restrict__ Wih,
                                                 const float* __restrict__ Whh,
                                                 const float* __restrict__ bih,
                                                 const float* __restrict__ bhh,
                                                 const float* __restrict__ w1g,
                                                 const float* __restrict__ b1g,
                                                 const float* __restrict__ w2g,
                                                 const float* __restrict__ b2g,
                                                 float* __restrict__ out) {
  const int tid = threadIdx.x;
  const int bg = blockIdx.x * BPW;
  const int wave = tid >> 6;
  const int ob = tid >> 7, oh = tid & 127;   // (batch, hidden unit) this thread owns

  float wih[21], whh[HID];
#pragma unroll
  for (int k = 0; k < 21; k++) wih[k] = Wih[tid * 21 + k];
#pragma unroll
  for (int k = 0; k < HID; k++) whh[k] = Whh[tid * HID + k];
  const float bias = bih[tid] + bhh[tid];

  float w1r[5], b1r[5], w2r[5];
#pragma unroll
  for (int j = 0; j < 5; j++) { w1r[j] = w1g[j * HID + oh]; b1r[j] = b1g[j]; w2r[j] = w2g[j]; }
  const float b2r = b2g[0];

  __shared__ float xs[BPW][21];
  __shared__ float hx[BPW][HID];
  __shared__ float gl[BPW][512];
  __shared__ float red[8][5];
  __shared__ int st_lastidx[BPW];  // last event time = idx*0.1 (exact f64 reconstruction)
  __shared__ int st_dynidx[BPW];   // dyn_time = idx*0.1
  __shared__ int st_has[BPW];

  for (int i = tid; i < BPW * HID; i += 512) (&hx[0][0])[i] = 0.f;
  if (tid < BPW) { st_lastidx[tid] = 0; st_dynidx[tid] = 0; st_has[tid] = 0; }
  float cx = 0.f;
  __syncthreads();

  for (int t = 0; t < T; t++) {
    // ---- build x = [att_out(8), m_emb(8), ct_emb(5)] in LDS ----
    if (tid < BPW * 8) {                                   // 0..31: attention output
      int b = tid >> 3, j = tid & 7;
      xs[b][j] = att[(size_t)(bg + b) * (T * 8) + (size_t)t * 8 + j];
    } else if (tid < BPW * 8 + BPW * 5) {                  // 32..51: m_emb time part
      int r2 = tid - BPW * 8; int b = r2 / 5, j = r2 % 5;
      float e[5]; temb((double)st_lastidx[b] * 0.1, e);
      xs[b][8 + j] = st_has[b] ? e[j] : 0.f;
    } else if (tid < BPW * 8 + BPW * 5 + BPW * 3) {        // 52..63: m_emb one-hot
      int r2 = tid - BPW * 8 - BPW * 5; int b = r2 / 3, j = r2 % 3;
      xs[b][13 + j] = (j == 0 && st_has[b]) ? 1.0f : 0.f;
    } else if (tid < BPW * 8 + BPW * 5 + BPW * 3 + BPW * 5) { // 64..83: ct_emb(dyn+0.1)
      int r2 = tid - (BPW * 8 + BPW * 5 + BPW * 3); int b = r2 / 5, j = r2 % 5;
      float e[5]; temb((double)(st_dynidx[b] + 1) * 0.1, e);
      xs[b][16 + j] = e[j];
    }
    __syncthreads();

    // ---- gate pre-activations: thread r computes row r for 4 batches ----
    float a0 = bias, a1 = bias, a2 = bias, a3 = bias;
#pragma unroll
    for (int k = 0; k < 21; k++) {
      a0 = fmaf(wih[k], xs[0][k], a0);
      a1 = fmaf(wih[k], xs[1][k], a1);
      a2 = fmaf(wih[k], xs[2][k], a2);
      a3 = fmaf(wih[k], xs[3][k], a3);
    }
#pragma unroll
    for (int k = 0; k < HID; k++) {
      a0 = fmaf(whh[k], hx[0][k], a0);
      a1 = fmaf(whh[k], hx[1][k], a1);
      a2 = fmaf(whh[k], hx[2][k], a2);
      a3 = fmaf(whh[k], hx[3][k], a3);
    }
    gl[0][tid] = a0; gl[1][tid] = a1; gl[2][tid] = a2; gl[3][tid] = a3;
    __syncthreads();

    // ---- LSTM cell update for (ob, oh); gates ordered i,f,g,o ----
    float gi = gl[ob][oh], gf = gl[ob][HID + oh],
          gg = gl[ob][2 * HID + oh], go = gl[ob][3 * HID + oh];
    cx = sig(gf) * cx + sig(gi) * tanhf(gg);
    float h = sig(go) * tanhf(cx);
    hx[ob][oh] = h;

    // ---- hazard head: s5 = w1*hx + b1 ; z = w2*s5 + b2 ----
    float p[5];
#pragma unroll
    for (int j = 0; j < 5; j++) {
      p[j] = w1r[j] * h;
#pragma unroll
      for (int o = 32; o > 0; o >>= 1) p[j] += __shfl_xor(p[j], o);
    }
    if ((tid & 63) == 0) {
#pragma unroll
      for (int j = 0; j < 5; j++) red[wave][j] = p[j];
    }
    __syncthreads();

    if (tid < BPW) {
      int b = tid;
      float z = b2r;
#pragma unroll
      for (int j = 0; j < 5; j++) {
        float s5 = red[2 * b][j] + red[2 * b + 1][j] + b1r[j];
        z += w2r[j] * s5;
      }
      float hz = sig(z);
      float uu = u[(size_t)(bg + b) * T + t];
      int ev = (uu < hz) ? 1 : 0;
      if (ev) { st_lastidx[b] = t + 1; st_has[b] = 1; st_dynidx[b] = 0; }
      else    { st_dynidx[b] = st_dynidx[b] + 1; }
      out[(size_t)t * BTOT + (bg + b)] = hz;
      out[(size_t)(T * BTOT) + (size_t)t * BTOT + (bg + b)] = ev ? 1.0f : 0.f;
    }
    __syncthreads();
  }
}

extern "C" void kernel_launch(void* const* d_in, const int* in_sizes, int n_in,
                              void* d_out, int out_size, void* d_ws, size_t ws_size,
                              hipStream_t stream) {
  const float* ta1 = (const float*)d_in[0];
  const float* ta2 = (const float*)d_in[1];
  const float* u   = (const float*)d_in[2];
  const float* Wih = (const float*)d_in[3];
  const float* Whh = (const float*)d_in[4];
  const float* bih = (const float*)d_in[5];
  const float* bhh = (const float*)d_in[6];
  const float* w1  = (const float*)d_in[7];
  const float* b1  = (const float*)d_in[8];
  const float* w2  = (const float*)d_in[9];
  const float* b2  = (const float*)d_in[10];
  float* out = (float*)d_out;
  float* att = (float*)d_ws;   // 1024*100*8 floats = 3.28 MB scratch

  attn_k<<<dim3(BTOT), dim3(256), 0, stream>>>(ta1, ta2, att);
  lstm_k<<<dim3(BTOT / BPW), dim3(512), 0, stream>>>(att, u, Wih, Whh, bih, bhh,
                                                     w1, b1, w2, b2, out);
}

// Round 3
// 997.902 us; speedup vs baseline: 2.4060x; 1.4758x over previous
//
#include <hip/hip_runtime.h>
#include <math.h>

#define BTOT 1024
#define LEN  2048
#define T    100
#define HID  128

// time-embedding dim constants (f64 argument scaling, f32 sincos)
#define C1 0.025118864315095794
#define C2 6.309573444801933e-04
#define C3 1.5848931924611134e-05
#define C4 3.9810717055349735e-07

// declares d0..d4 in current scope
#define TEMB(td) \
  float d0 = sinf((float)(td)); \
  float d1 = cosf((float)((td) * C1)); \
  float d2 = sinf((float)((td) * C2)); \
  float d3 = cosf((float)((td) * C3)); \
  float d4 = sinf((float)((td) * C4));

__device__ __forceinline__ float sig(float x) { return 1.0f / (1.0f + expf(-x)); }

// ---------------- Phase A: attention precompute ----------------
// One block per batch, 256 threads. Event-embedding dims 0..3 in LDS
// (float4, conflict-free ds_read_b128), dim 4 in 16 NAMED scalars.
// No indexed local arrays anywhere hot (round-2 lesson: the emb[16][5]
// alloca stayed in scratch -> 3.2 GB of spill traffic per dispatch).
__global__ __launch_bounds__(256, 2) void attn_k(const float* __restrict__ ta1,
                                                 const float* __restrict__ ta2,
                                                 float* __restrict__ att) {
  const int b = blockIdx.x, tid = threadIdx.x;
  const int wave = tid >> 6, lane = tid & 63;

  __shared__ float4 embA[16][256];   // 64 KB: dims 0..3 per event per thread
  __shared__ float qlds[T][5];
  __shared__ float ssum[2][4][7];

  if (tid < T) {
    double ct = (double)(tid + 1) * 0.1;
    TEMB(ct);
    qlds[tid][0] = d0 * 0.35355339059327373f;  // fold 1/sqrt(8)
    qlds[tid][1] = d1 * 0.35355339059327373f;
    qlds[tid][2] = d2 * 0.35355339059327373f;
    qlds[tid][3] = d3 * 0.35355339059327373f;
    qlds[tid][4] = d4 * 0.35355339059327373f;
  }

  float g0,g1,g2,g3,g4,g5,g6,g7,g8,g9,g10,g11,g12,g13,g14,g15;
#define STAGE(i, expr) { double td = (double)(expr); TEMB(td); \
    embA[i][tid] = make_float4(d0, d1, d2, d3); g##i = d4; }
  STAGE(0,  ta1[b * LEN + tid +    0])
  STAGE(1,  ta1[b * LEN + tid +  256])
  STAGE(2,  ta1[b * LEN + tid +  512])
  STAGE(3,  ta1[b * LEN + tid +  768])
  STAGE(4,  ta1[b * LEN + tid + 1024])
  STAGE(5,  ta1[b * LEN + tid + 1280])
  STAGE(6,  ta1[b * LEN + tid + 1536])
  STAGE(7,  ta1[b * LEN + tid + 1792])
  STAGE(8,  ta2[b * LEN + tid +    0])
  STAGE(9,  ta2[b * LEN + tid +  256])
  STAGE(10, ta2[b * LEN + tid +  512])
  STAGE(11, ta2[b * LEN + tid +  768])
  STAGE(12, ta2[b * LEN + tid + 1024])
  STAGE(13, ta2[b * LEN + tid + 1280])
  STAGE(14, ta2[b * LEN + tid + 1536])
  STAGE(15, ta2[b * LEN + tid + 1792])
#undef STAGE

  __syncthreads();

  for (int t = 0; t < T; t++) {
    const float q0 = qlds[t][0], q1 = qlds[t][1], q2 = qlds[t][2],
                q3 = qlds[t][3], q4 = qlds[t][4];
    float Wx = 0.f, Wy = 0.f, Wz = 0.f, Ww = 0.f, W4 = 0.f, sA = 0.f, sB = 0.f;
    // scores bounded: |q.k|/sqrt(8) <= 1.77 -> exp without max-subtraction is
    // safe in f32 (validated absmax 0.0 in rounds 1-2)
#define EV(i, S) { float4 a = embA[i][tid]; \
    float s = fmaf(q0, a.x, fmaf(q1, a.y, fmaf(q2, a.z, fmaf(q3, a.w, q4 * g##i)))); \
    float e = __expf(s); S += e; \
    Wx = fmaf(e, a.x, Wx); Wy = fmaf(e, a.y, Wy); \
    Wz = fmaf(e, a.z, Wz); Ww = fmaf(e, a.w, Ww); W4 = fmaf(e, g##i, W4); }
    EV(0, sA) EV(1, sA) EV(2, sA) EV(3, sA)
    EV(4, sA) EV(5, sA) EV(6, sA) EV(7, sA)
    EV(8, sB) EV(9, sB) EV(10, sB) EV(11, sB)
    EV(12, sB) EV(13, sB) EV(14, sB) EV(15, sB)
#undef EV

    float r0 = Wx, r1 = Wy, r2 = Wz, r3 = Ww, r4 = W4, r5 = sA, r6 = sB;
#pragma unroll
    for (int o = 32; o > 0; o >>= 1) {
      r0 += __shfl_xor(r0, o); r1 += __shfl_xor(r1, o);
      r2 += __shfl_xor(r2, o); r3 += __shfl_xor(r3, o);
      r4 += __shfl_xor(r4, o); r5 += __shfl_xor(r5, o);
      r6 += __shfl_xor(r6, o);
    }
    if (lane == 0) {
      ssum[t & 1][wave][0] = r0; ssum[t & 1][wave][1] = r1;
      ssum[t & 1][wave][2] = r2; ssum[t & 1][wave][3] = r3;
      ssum[t & 1][wave][4] = r4; ssum[t & 1][wave][5] = r5;
      ssum[t & 1][wave][6] = r6;
    }
    __syncthreads();
    // finalize reads buffer (t&1); iteration t+1 writes (t+1)&1 -- disjoint.
    if (tid == ((t & 3) << 6)) {
      float f0 = ssum[t&1][0][0] + ssum[t&1][1][0] + ssum[t&1][2][0] + ssum[t&1][3][0];
      float f1 = ssum[t&1][0][1] + ssum[t&1][1][1] + ssum[t&1][2][1] + ssum[t&1][3][1];
      float f2 = ssum[t&1][0][2] + ssum[t&1][1][2] + ssum[t&1][2][2] + ssum[t&1][3][2];
      float f3 = ssum[t&1][0][3] + ssum[t&1][1][3] + ssum[t&1][2][3] + ssum[t&1][3][3];
      float f4 = ssum[t&1][0][4] + ssum[t&1][1][4] + ssum[t&1][2][4] + ssum[t&1][3][4];
      float f5 = ssum[t&1][0][5] + ssum[t&1][1][5] + ssum[t&1][2][5] + ssum[t&1][3][5];
      float f6 = ssum[t&1][0][6] + ssum[t&1][1][6] + ssum[t&1][2][6] + ssum[t&1][3][6];
      float inv = 1.0f / (f5 + f6);
      float* o8 = &att[(size_t)b * (T * 8) + (size_t)t * 8];
      o8[0] = f0 * inv; o8[1] = f1 * inv; o8[2] = f2 * inv;
      o8[3] = f3 * inv; o8[4] = f4 * inv;
      o8[5] = 0.f; o8[6] = f5 * inv; o8[7] = f6 * inv;
    }
  }
}

// ---------------- Phase B: recurrent LSTM + hazard/event sampling ----------------
// 1024 threads/block, grid 256 (1 block/CU), 4 batches/block.
// Thread (r, half): half a concatenated weight row [W_ih(21)|pad(3)|W_hh(128)]
// = 19 NAMED float4 in VGPRs (~105 regs total < 128 cap at 4 waves/SIMD).
// x and hx live in one LDS buffer xbf[b*152 + .], read as broadcast b128.
__device__ __forceinline__ float wcat(const float* Wih, const float* Whh, int r, int e) {
  return (e < 21) ? Wih[r * 21 + e] : (e < 24) ? 0.f : Whh[r * HID + e - 24];
}

__global__ __launch_bounds__(1024, 4) void lstm_k(const float* __restrict__ att,
                                                  const float* __restrict__ u,
                                                  const float* __restrict__ Wih,
                                                  const float* __restrict__ Whh,
                                                  const float* __restrict__ bih,
                                                  const float* __restrict__ bhh,
                                                  const float* __restrict__ w1g,
                                                  const float* __restrict__ b1g,
                                                  const float* __restrict__ w2g,
                                                  const float* __restrict__ b2g,
                                                  float* __restrict__ out) {
  const int tid = threadIdx.x;
  const int bg = blockIdx.x * 4;
  const int r = tid >> 1, half = tid & 1;
  const int lane = tid & 63;
  const int CB = 19 * half;          // this thread's chunk base in the 38-chunk row
  const int ch = tid & 127;          // hidden unit (cell threads)

  __shared__ float4 xb4[4 * 38];     // per batch: [x(21)|pad(3)|hx(128)] = 38 float4
  __shared__ float glf[4 * 512];     // gate pre-activations per batch
  __shared__ float red[8][5];        // per-wave head partials
  __shared__ int stL[2][4], stD[2][4], stH[2][4];  // double-buffered event state
  float* xbf = (float*)xb4;

  const int eb = 76 * half;
#define LDW(c) const float4 w##c = make_float4( \
    wcat(Wih, Whh, r, eb + 4*(c) + 0), wcat(Wih, Whh, r, eb + 4*(c) + 1), \
    wcat(Wih, Whh, r, eb + 4*(c) + 2), wcat(Wih, Whh, r, eb + 4*(c) + 3));
  LDW(0) LDW(1) LDW(2) LDW(3) LDW(4) LDW(5) LDW(6) LDW(7) LDW(8) LDW(9)
  LDW(10) LDW(11) LDW(12) LDW(13) LDW(14) LDW(15) LDW(16) LDW(17) LDW(18)
#undef LDW
  const float binit = half ? 0.f : (bih[r] + bhh[r]);

  const float w1_0 = w1g[0*HID + ch], w1_1 = w1g[1*HID + ch], w1_2 = w1g[2*HID + ch],
              w1_3 = w1g[3*HID + ch], w1_4 = w1g[4*HID + ch];
  const float b1_0 = b1g[0], b1_1 = b1g[1], b1_2 = b1g[2], b1_3 = b1g[3], b1_4 = b1g[4];
  const float w2_0 = w2g[0], w2_1 = w2g[1], w2_2 = w2g[2], w2_3 = w2g[3], w2_4 = w2g[4];
  const float b2r = b2g[0];

  for (int i = tid; i < 4 * 152; i += 1024) xbf[i] = 0.f;
  if (tid < 4) { stL[0][tid] = 0; stD[0][tid] = 0; stH[0][tid] = 0; }
  float cx = 0.f;
  __syncthreads();

  // build x for t=0: att + ct_emb (m_emb stays 0: no event yet)
  if (tid < 32) {
    int b = tid >> 3, j = tid & 7;
    xbf[b * 152 + j] = att[(size_t)(bg + b) * (T * 8) + j];
  } else if (tid >= 64 && tid < 84) {
    int s = tid - 64, b = s / 5, j = s % 5;
    TEMB(0.1);
    xbf[b * 152 + 16 + j] = (j == 0) ? d0 : (j == 1) ? d1 : (j == 2) ? d2 : (j == 3) ? d3 : d4;
  }
  __syncthreads();

  // event decision computed redundantly by every x-builder thread (all inputs
  // are barrier-stable) so finalize+rebuild share one phase: 3 barriers/t.
#define CALCEV(bb) \
    float z_ = b2r; \
    z_ = fmaf(w2_0, red[2*(bb)][0] + red[2*(bb)+1][0] + b1_0, z_); \
    z_ = fmaf(w2_1, red[2*(bb)][1] + red[2*(bb)+1][1] + b1_1, z_); \
    z_ = fmaf(w2_2, red[2*(bb)][2] + red[2*(bb)+1][2] + b1_2, z_); \
    z_ = fmaf(w2_3, red[2*(bb)][3] + red[2*(bb)+1][3] + b1_3, z_); \
    z_ = fmaf(w2_4, red[2*(bb)][4] + red[2*(bb)+1][4] + b1_4, z_); \
    float hz_ = 1.f / (1.f + expf(-z_)); \
    int ev_ = (u[(size_t)(bg + (bb)) * T + t] < hz_) ? 1 : 0; \
    int tb_ = t & 1; \
    int lastp_ = ev_ ? (t + 1) : stL[tb_][bb]; \
    int hasp_ = stH[tb_][bb] | ev_; \
    int dynp_ = ev_ ? 0 : (stD[tb_][bb] + 1);

  for (int t = 0; t < T; t++) {
    // ---- P1: gate pre-activations (all 1024 threads) ----
    float a0 = binit, a1 = binit, a2 = binit, a3 = binit;
#define GB(c) { \
    float4 v0 = xb4[0*38 + CB + (c)], v1 = xb4[1*38 + CB + (c)]; \
    float4 v2 = xb4[2*38 + CB + (c)], v3 = xb4[3*38 + CB + (c)]; \
    a0 = fmaf(w##c.x, v0.x, a0); a0 = fmaf(w##c.y, v0.y, a0); \
    a0 = fmaf(w##c.z, v0.z, a0); a0 = fmaf(w##c.w, v0.w, a0); \
    a1 = fmaf(w##c.x, v1.x, a1); a1 = fmaf(w##c.y, v1.y, a1); \
    a1 = fmaf(w##c.z, v1.z, a1); a1 = fmaf(w##c.w, v1.w, a1); \
    a2 = fmaf(w##c.x, v2.x, a2); a2 = fmaf(w##c.y, v2.y, a2); \
    a2 = fmaf(w##c.z, v2.z, a2); a2 = fmaf(w##c.w, v2.w, a2); \
    a3 = fmaf(w##c.x, v3.x, a3); a3 = fmaf(w##c.y, v3.y, a3); \
    a3 = fmaf(w##c.z, v3.z, a3); a3 = fmaf(w##c.w, v3.w, a3); }
    GB(0) GB(1) GB(2) GB(3) GB(4) GB(5) GB(6) GB(7) GB(8) GB(9)
    GB(10) GB(11) GB(12) GB(13) GB(14) GB(15) GB(16) GB(17) GB(18)
#undef GB
    a0 += __shfl_xor(a0, 1); a1 += __shfl_xor(a1, 1);
    a2 += __shfl_xor(a2, 1); a3 += __shfl_xor(a3, 1);
    if (!half) {
      glf[0*512 + r] = a0; glf[1*512 + r] = a1;
      glf[2*512 + r] = a2; glf[3*512 + r] = a3;
    }
    __syncthreads();

    // ---- P2: cell update + head partials (threads 0..511) ----
    if (tid < 512) {
      int b = tid >> 7;
      float gi = glf[b*512 + ch], gf = glf[b*512 + 128 + ch],
            gg = glf[b*512 + 256 + ch], go = glf[b*512 + 384 + ch];
      cx = sig(gf) * cx + sig(gi) * tanhf(gg);
      float hn = sig(go) * tanhf(cx);
      xbf[b * 152 + 24 + ch] = hn;
      float p0 = w1_0 * hn, p1 = w1_1 * hn, p2 = w1_2 * hn,
            p3 = w1_3 * hn, p4 = w1_4 * hn;
#pragma unroll
      for (int o = 32; o > 0; o >>= 1) {
        p0 += __shfl_xor(p0, o); p1 += __shfl_xor(p1, o);
        p2 += __shfl_xor(p2, o); p3 += __shfl_xor(p3, o);
        p4 += __shfl_xor(p4, o);
      }
      if (lane == 0) {
        int w = tid >> 6;
        red[w][0] = p0; red[w][1] = p1; red[w][2] = p2;
        red[w][3] = p3; red[w][4] = p4;
      }
    }
    __syncthreads();

    // ---- P3: finalize + build x for t+1 ----
    if (tid < 4) {
      int b = tid;
      CALCEV(b);
      out[(size_t)t * BTOT + bg + b] = hz_;
      out[(size_t)T * BTOT + (size_t)t * BTOT + bg + b] = ev_ ? 1.f : 0.f;
      stL[tb_ ^ 1][b] = lastp_; stH[tb_ ^ 1][b] = hasp_; stD[tb_ ^ 1][b] = dynp_;
    }
    if (t < T - 1) {
      if (tid < 32) {
        int b = tid >> 3, j = tid & 7;
        xbf[b * 152 + j] = att[(size_t)(bg + b) * (T * 8) + (size_t)(t + 1) * 8 + j];
      } else if (tid < 52) {
        int s = tid - 32, b = s / 5, j = s % 5;
        CALCEV(b);
        float v = 0.f;
        if (hasp_) {
          double td = (double)lastp_ * 0.1;
          TEMB(td);
          v = (j == 0) ? d0 : (j == 1) ? d1 : (j == 2) ? d2 : (j == 3) ? d3 : d4;
        }
        xbf[b * 152 + 8 + j] = v;
      } else if (tid < 64) {
        int s = tid - 52, b = s / 3, j = s % 3;
        CALCEV(b);
        xbf[b * 152 + 13 + j] = (j == 0 && hasp_) ? 1.f : 0.f;
      } else if (tid < 84) {
        int s = tid - 64, b = s / 5, j = s % 5;
        CALCEV(b);
        double td = (double)(dynp_ + 1) * 0.1;
        TEMB(td);
        xbf[b * 152 + 16 + j] =
            (j == 0) ? d0 : (j == 1) ? d1 : (j == 2) ? d2 : (j == 3) ? d3 : d4;
      }
    }
    __syncthreads();
  }
#undef CALCEV
}

extern "C" void kernel_launch(void* const* d_in, const int* in_sizes, int n_in,
                              void* d_out, int out_size, void* d_ws, size_t ws_size,
                              hipStream_t stream) {
  const float* ta1 = (const float*)d_in[0];
  const float* ta2 = (const float*)d_in[1];
  const float* u   = (const float*)d_in[2];
  const float* Wih = (const float*)d_in[3];
  const float* Whh = (const float*)d_in[4];
  const float* bih = (const float*)d_in[5];
  const float* bhh = (const float*)d_in[6];
  const float* w1  = (const float*)d_in[7];
  const float* b1  = (const float*)d_in[8];
  const float* w2  = (const float*)d_in[9];
  const float* b2  = (const float*)d_in[10];
  float* out = (float*)d_out;
  float* att = (float*)d_ws;   // 1024*100*8 floats = 3.28 MB scratch

  attn_k<<<dim3(BTOT), dim3(256), 0, stream>>>(ta1, ta2, att);
  lstm_k<<<dim3(BTOT / 4), dim3(1024), 0, stream>>>(att, u, Wih, Whh, bih, bhh,
                                                    w1, b1, w2, b2, out);
}

// Round 6
// 836.564 us; speedup vs baseline: 2.8701x; 1.1929x over previous
//
#include <hip/hip_runtime.h>
#include <math.h>

#define BTOT 1024
#define LEN  2048
#define T    100
#define HID  128

// time-embedding dim constants (f64 argument scaling, f32 sincos)
#define C1 0.025118864315095794
#define C2 6.309573444801933e-04
#define C3 1.5848931924611134e-05
#define C4 3.9810717055349735e-07

#define TEMB(td) \
  float d0 = sinf((float)(td)); \
  float d1 = cosf((float)((td) * C1)); \
  float d2 = sinf((float)((td) * C2)); \
  float d3 = cosf((float)((td) * C3)); \
  float d4 = sinf((float)((td) * C4));

__device__ __forceinline__ float sig(float x) { return 1.0f / (1.0f + expf(-x)); }

// DPP-based add: x + x_from_permuted_lane (VALU pipe, not DS pipe).
// ctrl must be a compile-time constant -> template parameter (round-5 fix).
template <int CTRL>
__device__ __forceinline__ float dppadd(float x) {
  int r = __builtin_amdgcn_update_dpp(0, __float_as_int(x), CTRL, 0xF, 0xF, false);
  return x + __int_as_float(r);
}
// full 64-lane sum; result in ALL lanes. xor1,xor2 via quad_perm; 4,8 via
// row_ror (reduction-valid rotation); 16,32 via shfl (DS pipe, 2 insts).
__device__ __forceinline__ float wred(float x) {
  x = dppadd<0xB1>(x);    // quad_perm [1,0,3,2]  (xor 1)
  x = dppadd<0x4E>(x);    // quad_perm [2,3,0,1]  (xor 2)
  x = dppadd<0x124>(x);   // row_ror:4
  x = dppadd<0x128>(x);   // row_ror:8
  x += __shfl_xor(x, 16);
  x += __shfl_xor(x, 32);
  return x;
}

// ---------------- Phase A: attention precompute ----------------
// One block per batch, 256 threads, 4 blocks/CU resident (grid 1024 = 4*256).
// All 16 events x 5 dims live in 80 NAMED VGPR scalars, PINNED via empty
// asm so the compiler cannot sink the init loads/sincos into the t-loop
// (round-3 lesson: named values alone get rematerialized; VGPR fell to 64
// and the kernel went L2-latency-bound).
__global__ __launch_bounds__(256, 4) void attn_k(const float* __restrict__ ta1,
                                                 const float* __restrict__ ta2,
                                                 float* __restrict__ att) {
  const int b = blockIdx.x, tid = threadIdx.x;
  const int wave = tid >> 6, lane = tid & 63;

  __shared__ float qlds[T][8];        // q (scaled), padded stride 8
  __shared__ float strip[4][T][8];    // per-wave partials, combined at end

  if (tid < T) {
    double ct = (double)(tid + 1) * 0.1;
    TEMB(ct);
    qlds[tid][0] = d0 * 0.35355339059327373f;  // fold 1/sqrt(8)
    qlds[tid][1] = d1 * 0.35355339059327373f;
    qlds[tid][2] = d2 * 0.35355339059327373f;
    qlds[tid][3] = d3 * 0.35355339059327373f;
    qlds[tid][4] = d4 * 0.35355339059327373f;
  }

#define E5(i) float e##i##_0, e##i##_1, e##i##_2, e##i##_3, e##i##_4;
  E5(0) E5(1) E5(2) E5(3) E5(4) E5(5) E5(6) E5(7)
  E5(8) E5(9) E5(10) E5(11) E5(12) E5(13) E5(14) E5(15)
#undef E5
#define STAGE(i, expr) { double td_ = (double)(expr); \
    e##i##_0 = sinf((float)td_); \
    e##i##_1 = cosf((float)(td_ * C1)); \
    e##i##_2 = sinf((float)(td_ * C2)); \
    e##i##_3 = cosf((float)(td_ * C3)); \
    e##i##_4 = sinf((float)(td_ * C4)); }
  STAGE(0,  ta1[b * LEN + tid +    0])
  STAGE(1,  ta1[b * LEN + tid +  256])
  STAGE(2,  ta1[b * LEN + tid +  512])
  STAGE(3,  ta1[b * LEN + tid +  768])
  STAGE(4,  ta1[b * LEN + tid + 1024])
  STAGE(5,  ta1[b * LEN + tid + 1280])
  STAGE(6,  ta1[b * LEN + tid + 1536])
  STAGE(7,  ta1[b * LEN + tid + 1792])
  STAGE(8,  ta2[b * LEN + tid +    0])
  STAGE(9,  ta2[b * LEN + tid +  256])
  STAGE(10, ta2[b * LEN + tid +  512])
  STAGE(11, ta2[b * LEN + tid +  768])
  STAGE(12, ta2[b * LEN + tid + 1024])
  STAGE(13, ta2[b * LEN + tid + 1280])
  STAGE(14, ta2[b * LEN + tid + 1536])
  STAGE(15, ta2[b * LEN + tid + 1792])
#undef STAGE
#define PIN5(i) asm volatile("" : "+v"(e##i##_0), "+v"(e##i##_1), \
    "+v"(e##i##_2), "+v"(e##i##_3), "+v"(e##i##_4));
  PIN5(0) PIN5(1) PIN5(2) PIN5(3) PIN5(4) PIN5(5) PIN5(6) PIN5(7)
  PIN5(8) PIN5(9) PIN5(10) PIN5(11) PIN5(12) PIN5(13) PIN5(14) PIN5(15)
#undef PIN5

  __syncthreads();

  for (int t = 0; t < T; t++) {
    const float4 qv = *(const float4*)&qlds[t][0];
    const float q4 = qlds[t][4];
    float Wx = 0.f, Wy = 0.f, Wz = 0.f, Ww = 0.f, W4 = 0.f, sA = 0.f, sB = 0.f;
    // scores bounded (|q.k|/sqrt8 <= 1.77): exp without max-sub, f32-safe
    // (validated absmax 0.0 rounds 1-3)
#define EV(i, S) { \
    float s = fmaf(qv.x, e##i##_0, fmaf(qv.y, e##i##_1, \
              fmaf(qv.z, e##i##_2, fmaf(qv.w, e##i##_3, q4 * e##i##_4)))); \
    float e = __expf(s); S += e; \
    Wx = fmaf(e, e##i##_0, Wx); Wy = fmaf(e, e##i##_1, Wy); \
    Wz = fmaf(e, e##i##_2, Wz); Ww = fmaf(e, e##i##_3, Ww); \
    W4 = fmaf(e, e##i##_4, W4); }
    EV(0, sA) EV(1, sA) EV(2, sA) EV(3, sA)
    EV(4, sA) EV(5, sA) EV(6, sA) EV(7, sA)
    EV(8, sB) EV(9, sB) EV(10, sB) EV(11, sB)
    EV(12, sB) EV(13, sB) EV(14, sB) EV(15, sB)
#undef EV

    float r0 = wred(Wx), r1 = wred(Wy), r2 = wred(Wz), r3 = wred(Ww);
    float r4 = wred(W4), r5 = wred(sA), r6 = wred(sB);
    if (lane == 0) {
      *(float4*)&strip[wave][t][0] = make_float4(r0, r1, r2, r3);
      strip[wave][t][4] = r4; strip[wave][t][5] = r5; strip[wave][t][6] = r6;
    }
  }
  __syncthreads();

  if (tid < T) {
    float4 a0 = *(float4*)&strip[0][tid][0], b0 = *(float4*)&strip[0][tid][4];
    float4 a1 = *(float4*)&strip[1][tid][0], b1 = *(float4*)&strip[1][tid][4];
    float4 a2 = *(float4*)&strip[2][tid][0], b2 = *(float4*)&strip[2][tid][4];
    float4 a3 = *(float4*)&strip[3][tid][0], b3 = *(float4*)&strip[3][tid][4];
    float f0 = a0.x + a1.x + a2.x + a3.x;
    float f1 = a0.y + a1.y + a2.y + a3.y;
    float f2 = a0.z + a1.z + a2.z + a3.z;
    float f3 = a0.w + a1.w + a2.w + a3.w;
    float f4 = b0.x + b1.x + b2.x + b3.x;
    float f5 = b0.y + b1.y + b2.y + b3.y;
    float f6 = b0.z + b1.z + b2.z + b3.z;
    float inv = 1.0f / (f5 + f6);
    float* o8 = &att[(size_t)b * (T * 8) + (size_t)tid * 8];
    o8[0] = f0 * inv; o8[1] = f1 * inv; o8[2] = f2 * inv;
    o8[3] = f3 * inv; o8[4] = f4 * inv;
    o8[5] = 0.f; o8[6] = f5 * inv; o8[7] = f6 * inv;
  }
}

// ---------------- Phase B: recurrent LSTM + hazard/event sampling ----------------
// 1024 threads/block, grid 256, 4 batches/block, 1 block/CU.
// Thread (r, half) owns half a concatenated row [W_ih(21)|pad(3)|W_hh(128)]
// = 76 PINNED scalar VGPRs (named wr<c>_<j>; head weights are w2_*).
__device__ __forceinline__ float wcat(const float* Wih, const float* Whh, int r, int e) {
  return (e < 21) ? Wih[r * 21 + e] : (e < 24) ? 0.f : Whh[r * HID + e - 24];
}

__global__ __launch_bounds__(1024, 2) void lstm_k(const float* __restrict__ att,
                                                  const float* __restrict__ u,
                                                  const float* __restrict__ Wih,
                                                  const float* __restrict__ Whh,
                                                  const float* __restrict__ bih,
                                                  const float* __restrict__ bhh,
                                                  const float* __restrict__ w1g,
                                                  const float* __restrict__ b1g,
                                                  const float* __restrict__ w2g,
                                                  const float* __restrict__ b2g,
                                                  float* __restrict__ out) {
  const int tid = threadIdx.x;
  const int bg = blockIdx.x * 4;
  const int r = tid >> 1, half = tid & 1;
  const int CB = 19 * half;
  const int ch = tid & 127;

  __shared__ float4 xb4[4 * 38];     // per batch: [x(21)|pad(3)|hx(128)]
  __shared__ float glf[4 * 512];
  __shared__ float red[8][5];
  __shared__ int stL[2][4], stD[2][4], stH[2][4];
  float* xbf = (float*)xb4;

  const int eb = 76 * half;
#define DECLW(c) float wr##c##_0 = wcat(Wih, Whh, r, eb + 4*(c) + 0), \
                       wr##c##_1 = wcat(Wih, Whh, r, eb + 4*(c) + 1), \
                       wr##c##_2 = wcat(Wih, Whh, r, eb + 4*(c) + 2), \
                       wr##c##_3 = wcat(Wih, Whh, r, eb + 4*(c) + 3);
  DECLW(0) DECLW(1) DECLW(2) DECLW(3) DECLW(4) DECLW(5) DECLW(6) DECLW(7)
  DECLW(8) DECLW(9) DECLW(10) DECLW(11) DECLW(12) DECLW(13) DECLW(14)
  DECLW(15) DECLW(16) DECLW(17) DECLW(18)
#undef DECLW
  float binit = half ? 0.f : (bih[r] + bhh[r]);

  float w1_0 = w1g[0*HID + ch], w1_1 = w1g[1*HID + ch], w1_2 = w1g[2*HID + ch],
        w1_3 = w1g[3*HID + ch], w1_4 = w1g[4*HID + ch];
  const float b1_0 = b1g[0], b1_1 = b1g[1], b1_2 = b1g[2], b1_3 = b1g[3], b1_4 = b1g[4];
  const float w2_0 = w2g[0], w2_1 = w2g[1], w2_2 = w2g[2], w2_3 = w2g[3], w2_4 = w2g[4];
  const float b2r = b2g[0];

  // PIN: loads must stay in VGPRs across the loop (not re-issued per t)
#define PINW(c) asm volatile("" : "+v"(wr##c##_0), "+v"(wr##c##_1), \
    "+v"(wr##c##_2), "+v"(wr##c##_3));
  PINW(0) PINW(1) PINW(2) PINW(3) PINW(4) PINW(5) PINW(6) PINW(7)
  PINW(8) PINW(9) PINW(10) PINW(11) PINW(12) PINW(13) PINW(14)
  PINW(15) PINW(16) PINW(17) PINW(18)
#undef PINW
  asm volatile("" : "+v"(binit), "+v"(w1_0), "+v"(w1_1), "+v"(w1_2),
                    "+v"(w1_3), "+v"(w1_4));

  for (int i = tid; i < 4 * 152; i += 1024) xbf[i] = 0.f;
  if (tid < 4) { stL[0][tid] = 0; stD[0][tid] = 0; stH[0][tid] = 0; }
  float cx = 0.f;
  __syncthreads();

  // x for t=0: att + ct_emb (m_emb all-zero: no event yet)
  if (tid < 32) {
    int b = tid >> 3, j = tid & 7;
    xbf[b * 152 + j] = att[(size_t)(bg + b) * (T * 8) + j];
  } else if (tid >= 64 && tid < 84) {
    int s = tid - 64, b = s / 5, j = s % 5;
    TEMB(0.1);
    xbf[b * 152 + 16 + j] = (j == 0) ? d0 : (j == 1) ? d1 : (j == 2) ? d2 : (j == 3) ? d3 : d4;
  }
  __syncthreads();

#define CALCEV(bb) \
    float z_ = b2r; \
    z_ = fmaf(w2_0, red[2*(bb)][0] + red[2*(bb)+1][0] + b1_0, z_); \
    z_ = fmaf(w2_1, red[2*(bb)][1] + red[2*(bb)+1][1] + b1_1, z_); \
    z_ = fmaf(w2_2, red[2*(bb)][2] + red[2*(bb)+1][2] + b1_2, z_); \
    z_ = fmaf(w2_3, red[2*(bb)][3] + red[2*(bb)+1][3] + b1_3, z_); \
    z_ = fmaf(w2_4, red[2*(bb)][4] + red[2*(bb)+1][4] + b1_4, z_); \
    float hz_ = 1.f / (1.f + expf(-z_)); \
    int ev_ = (u[(size_t)(bg + (bb)) * T + t] < hz_) ? 1 : 0; \
    int tb_ = t & 1; \
    int lastp_ = ev_ ? (t + 1) : stL[tb_][bb]; \
    int hasp_ = stH[tb_][bb] | ev_; \
    int dynp_ = ev_ ? 0 : (stD[tb_][bb] + 1);

  for (int t = 0; t < T; t++) {
    // ---- P1: gate pre-activations ----
    float a0 = binit, a1 = binit, a2 = binit, a3 = binit;
#define GB(c) { \
    float4 v0 = xb4[0*38 + CB + (c)], v1 = xb4[1*38 + CB + (c)]; \
    float4 v2 = xb4[2*38 + CB + (c)], v3 = xb4[3*38 + CB + (c)]; \
    a0 = fmaf(wr##c##_0, v0.x, a0); a0 = fmaf(wr##c##_1, v0.y, a0); \
    a0 = fmaf(wr##c##_2, v0.z, a0); a0 = fmaf(wr##c##_3, v0.w, a0); \
    a1 = fmaf(wr##c##_0, v1.x, a1); a1 = fmaf(wr##c##_1, v1.y, a1); \
    a1 = fmaf(wr##c##_2, v1.z, a1); a1 = fmaf(wr##c##_3, v1.w, a1); \
    a2 = fmaf(wr##c##_0, v2.x, a2); a2 = fmaf(wr##c##_1, v2.y, a2); \
    a2 = fmaf(wr##c##_2, v2.z, a2); a2 = fmaf(wr##c##_3, v2.w, a2); \
    a3 = fmaf(wr##c##_0, v3.x, a3); a3 = fmaf(wr##c##_1, v3.y, a3); \
    a3 = fmaf(wr##c##_2, v3.z, a3); a3 = fmaf(wr##c##_3, v3.w, a3); }
    GB(0) GB(1) GB(2) GB(3) GB(4) GB(5) GB(6) GB(7) GB(8) GB(9)
    GB(10) GB(11) GB(12) GB(13) GB(14) GB(15) GB(16) GB(17) GB(18)
#undef GB
    // pair-sum lanes (2r, 2r+1): quad_perm xor1 on VALU pipe
    a0 = dppadd<0xB1>(a0); a1 = dppadd<0xB1>(a1);
    a2 = dppadd<0xB1>(a2); a3 = dppadd<0xB1>(a3);
    if (!half) {
      glf[0*512 + r] = a0; glf[1*512 + r] = a1;
      glf[2*512 + r] = a2; glf[3*512 + r] = a3;
    }
    __syncthreads();

    // ---- P2: cell update + head partials (threads 0..511) ----
    if (tid < 512) {
      int b = tid >> 7;
      float gi = glf[b*512 + ch], gf = glf[b*512 + 128 + ch],
            gg = glf[b*512 + 256 + ch], go = glf[b*512 + 384 + ch];
      cx = sig(gf) * cx + sig(gi) * tanhf(gg);
      float hn = sig(go) * tanhf(cx);
      xbf[b * 152 + 24 + ch] = hn;
      float p0 = wred(w1_0 * hn), p1 = wred(w1_1 * hn), p2 = wred(w1_2 * hn),
            p3 = wred(w1_3 * hn), p4 = wred(w1_4 * hn);
      if ((tid & 63) == 0) {
        int w = tid >> 6;
        red[w][0] = p0; red[w][1] = p1; red[w][2] = p2;
        red[w][3] = p3; red[w][4] = p4;
      }
    }
    __syncthreads();

    // ---- P3: finalize + build x for t+1 (event calc redundant per thread) ----
    if (tid < 4) {
      int b = tid;
      CALCEV(b);
      out[(size_t)t * BTOT + bg + b] = hz_;
      out[(size_t)T * BTOT + (size_t)t * BTOT + bg + b] = ev_ ? 1.f : 0.f;
      stL[tb_ ^ 1][b] = lastp_; stH[tb_ ^ 1][b] = hasp_; stD[tb_ ^ 1][b] = dynp_;
    }
    if (t < T - 1) {
      if (tid < 32) {
        int b = tid >> 3, j = tid & 7;
        xbf[b * 152 + j] = att[(size_t)(bg + b) * (T * 8) + (size_t)(t + 1) * 8 + j];
      } else if (tid < 52) {
        int s = tid - 32, b = s / 5, j = s % 5;
        CALCEV(b);
        float v = 0.f;
        if (hasp_) {
          double td = (double)lastp_ * 0.1;
          TEMB(td);
          v = (j == 0) ? d0 : (j == 1) ? d1 : (j == 2) ? d2 : (j == 3) ? d3 : d4;
        }
        xbf[b * 152 + 8 + j] = v;
      } else if (tid < 64) {
        int s = tid - 52, b = s / 3, j = s % 3;
        CALCEV(b);
        xbf[b * 152 + 13 + j] = (j == 0 && hasp_) ? 1.f : 0.f;
      } else if (tid < 84) {
        int s = tid - 64, b = s / 5, j = s % 5;
        CALCEV(b);
        double td = (double)(dynp_ + 1) * 0.1;
        TEMB(td);
        xbf[b * 152 + 16 + j] =
            (j == 0) ? d0 : (j == 1) ? d1 : (j == 2) ? d2 : (j == 3) ? d3 : d4;
      }
    }
    __syncthreads();
  }
#undef CALCEV
}

extern "C" void kernel_launch(void* const* d_in, const int* in_sizes, int n_in,
                              void* d_out, int out_size, void* d_ws, size_t ws_size,
                              hipStream_t stream) {
  const float* ta1 = (const float*)d_in[0];
  const float* ta2 = (const float*)d_in[1];
  const float* u   = (const float*)d_in[2];
  const float* Wih = (const float*)d_in[3];
  const float* Whh = (const float*)d_in[4];
  const float* bih = (const float*)d_in[5];
  const float* bhh = (const float*)d_in[6];
  const float* w1  = (const float*)d_in[7];
  const float* b1  = (const float*)d_in[8];
  const float* w2  = (const float*)d_in[9];
  const float* b2  = (const float*)d_in[10];
  float* out = (float*)d_out;
  float* att = (float*)d_ws;   // 1024*100*8 floats = 3.28 MB scratch

  attn_k<<<dim3(BTOT), dim3(256), 0, stream>>>(ta1, ta2, att);
  lstm_k<<<dim3(BTOT / 4), dim3(1024), 0, stream>>>(att, u, Wih, Whh, bih, bhh,
                                                    w1, b1, w2, b2, out);
}